// Round 4
// baseline (380.331 us; speedup 1.0000x reference)
//
#include <hip/hip_runtime.h>
#include <math.h>

static constexpr int NN   = 4096;
static constexpr int INC  = 256;
static constexpr int OUTC = 64;

typedef _Float16 half8 __attribute__((ext_vector_type(8)));
typedef float floatx4 __attribute__((ext_vector_type(4)));

#if __has_builtin(__builtin_amdgcn_exp2f)
#define EXP2F(x) __builtin_amdgcn_exp2f(x)
#else
#define EXP2F(x) exp2f(x)
#endif

__device__ __forceinline__ float elu1(float x) {
    return x > 0.f ? x : (__expf(x) - 1.f);
}

// K_prep: fused front-end, one launch (R1 structure restored).
//  - blocks 0..255   : Wh = H@W -> fp16 WhT, f1 = Wh@a1, f2 = Wh@a2,
//                      per-tile f2 max -> blkmax[b], zero cnt[b]
//  - blocks 256..2303: pack adj (64 MB) -> 2 MB bitmask (coalesced via LDS)
__global__ __launch_bounds__(256) void k_prep(const int* __restrict__ adj,
                                              unsigned int* __restrict__ bits,
                                              const float* __restrict__ H,
                                              const float* __restrict__ W,
                                              const float* __restrict__ a,
                                              unsigned short* __restrict__ WhT,
                                              float* __restrict__ f1,
                                              float* __restrict__ f2,
                                              float* __restrict__ blkmax,
                                              unsigned int* __restrict__ cnt) {
    __shared__ __align__(16) float Hl[16 * INC];   // 16 KB (pack branch aliases 2 KB)
    __shared__ _Float16 Tl[16 * 68];               // 2.2 KB transpose buffer
    __shared__ float wmax4[4];
    const int t = threadIdx.x;
    if (blockIdx.x >= 256) {
        // ---- pack branch: 2 adj rows (8192 ints = 2048 int4) per block ----
        unsigned char* nib = (unsigned char*)Hl;           // 2 KB LDS alias
        const int blk = blockIdx.x - 256;
        const int4* src = (const int4*)adj + (size_t)blk * 2048;
        #pragma unroll
        for (int k = 0; k < 8; ++k) {
            const int4 v = src[k * 256 + t];               // fully coalesced
            nib[k * 256 + t] = (unsigned char)((unsigned int)(v.x > 0)
                             | ((unsigned int)(v.y > 0) << 1)
                             | ((unsigned int)(v.z > 0) << 2)
                             | ((unsigned int)(v.w > 0) << 3));
        }
        __syncthreads();
        const unsigned int* n32 = (const unsigned int*)nib;
        unsigned int lo = n32[t * 2 + 0];
        unsigned int hi = n32[t * 2 + 1];
        lo |= lo >> 4;  lo &= 0x00FF00FFu;  lo |= lo >> 8;  lo &= 0x0000FFFFu;
        hi |= hi >> 4;  hi &= 0x00FF00FFu;  hi |= hi >> 8;  hi &= 0x0000FFFFu;
        bits[blk * 256 + t] = lo | (hi << 16);
        return;
    }
    // ---- wh branch ----
    if (t == 0) cnt[blockIdx.x] = 0;      // per-tile finalize counter (ws is poisoned)
    const int i0 = blockIdx.x * 16;
    {
        const float4* H4 = (const float4*)(H + i0 * INC);
        float4* Hl4 = (float4*)Hl;
        #pragma unroll
        for (int u = 0; u < 4; ++u) Hl4[u * 256 + t] = H4[u * 256 + t];
    }
    __syncthreads();
    const int c = t & 63;       // channel (lane)
    const int g = t >> 6;       // wave -> row group
    const float a1c = a[c];
    const float a2c = a[OUTC + c];
    float acc[4] = {0.f, 0.f, 0.f, 0.f};
    const float4* Hl4 = (const float4*)Hl;
    #pragma unroll 4
    for (int k4 = 0; k4 < INC / 4; ++k4) {
        const float w0 = W[(k4 * 4 + 0) * OUTC + c];   // coalesced, L2-hit
        const float w1 = W[(k4 * 4 + 1) * OUTC + c];
        const float w2 = W[(k4 * 4 + 2) * OUTC + c];
        const float w3 = W[(k4 * 4 + 3) * OUTC + c];
        #pragma unroll
        for (int s = 0; s < 4; ++s) {
            const float4 h = Hl4[(g + 4 * s) * (INC / 4) + k4];
            acc[s] = fmaf(h.x, w0, fmaf(h.y, w1, fmaf(h.z, w2, fmaf(h.w, w3, acc[s]))));
        }
    }
    float vmax = -1e30f;
    #pragma unroll
    for (int s = 0; s < 4; ++s) {
        const int r = g + 4 * s;
        Tl[r * 68 + c] = (_Float16)acc[s];
        float v1 = acc[s] * a1c;
        float v2 = acc[s] * a2c;
        #pragma unroll
        for (int off = 32; off; off >>= 1) {
            v1 += __shfl_xor(v1, off);
            v2 += __shfl_xor(v2, off);
        }
        vmax = fmaxf(vmax, v2);
        if (c == 0) { f1[i0 + r] = v1; f2[i0 + r] = v2; }
    }
    if (c == 0) wmax4[g] = vmax;
    __syncthreads();
    if (t == 0)
        blkmax[blockIdx.x] = fmaxf(fmaxf(wmax4[0], wmax4[1]), fmaxf(wmax4[2], wmax4[3]));
    const int c2 = t >> 2;
    const int rs = (t & 3) * 4;
    ushort4 u;
    u.x = *(const unsigned short*)&Tl[(rs + 0) * 68 + c2];
    u.y = *(const unsigned short*)&Tl[(rs + 1) * 68 + c2];
    u.z = *(const unsigned short*)&Tl[(rs + 2) * 68 + c2];
    u.w = *(const unsigned short*)&Tl[(rs + 3) * 68 + c2];
    *(ushort4*)(WhT + c2 * NN + i0 + rs) = u;
}

// K_att: 16 rows x 1024 j (quarter) per block, 8 waves, grid 1024.
// Occupancy lever: LDS ~37 KB + launch_bounds(512,6) -> 3 blocks/CU
// = 6 waves/SIMD (was 4). Each block writes f32 partials (out-sums, den)
// to ws; last block per tile (device-scope atomic counter) combines the
// 4 partials and writes elu(sum/den). bits + WhT stay L2-resident (the
// R2/R3 lesson: never stream adj through L2 concurrently with k_att).
__global__ __launch_bounds__(512, 6) void k_att(const unsigned char* __restrict__ bits,
                                                const _Float16* __restrict__ WhT,
                                                const float* __restrict__ f1,
                                                const float* __restrict__ f2,
                                                const float* __restrict__ blkmax,
                                                float* __restrict__ pout,
                                                float* __restrict__ pden,
                                                unsigned int* __restrict__ cnt,
                                                float* __restrict__ out) {
    __shared__ __align__(16) float sf2q[1024];      // 4 KB  (quarter, pre-scaled by log2e)
    __shared__ __align__(16) float sacc[8 * 1024];  // 32 KB
    __shared__ float sden[8 * 16];
    __shared__ float smax[8];
    __shared__ unsigned int slast;
    const int t = threadIdx.x;
    const int w = t >> 6;          // wave 0..7
    const int l = t & 63;
    const int m = l & 15;          // A row (= output row within tile)
    const int quad = l >> 4;       // k-group
    const int tile = blockIdx.x >> 2;
    const int q = blockIdx.x & 3;  // j-quarter
    const int i0 = tile * 16;
    const float LOG2E = 1.44269504f;

    // prologue: global f2 max from the 256 per-tile maxes (precomputed in k_prep)
    {
        float mloc = (t < 256) ? blkmax[t] : -1e30f;
        #pragma unroll
        for (int off = 32; off; off >>= 1) mloc = fmaxf(mloc, __shfl_xor(mloc, off));
        if (l == 0) smax[w] = mloc;
    }
    // own f2 quarter -> LDS, pre-scaled by log2e
    if (t < 256) {
        float4 v = ((const float4*)f2)[q * 256 + t];
        v.x *= LOG2E; v.y *= LOG2E; v.z *= LOG2E; v.w *= LOG2E;
        ((float4*)sf2q)[t] = v;
    }
    __syncthreads();
    float maxf2 = smax[0];
    #pragma unroll
    for (int k = 1; k < 8; ++k) maxf2 = fmaxf(maxf2, smax[k]);

    const float f1r = f1[i0 + m];
    const float zm = f1r + maxf2;
    const float mrow = fmaxf(zm, 0.2f * zm);        // exact row max (lrelu monotone)
    const float nm2 = -mrow * LOG2E;
    const float f1c = fmaf(f1r, LOG2E, nm2);        // u = f1c + f2j*log2e
    const float c8 = 0.8f * nm2;                    // 0.2u + c8 = (0.2z)*log2e - mrow*log2e
    float den0 = 0.f, den1 = 0.f;
    floatx4 acc[4] = {{0.f,0.f,0.f,0.f},{0.f,0.f,0.f,0.f},{0.f,0.f,0.f,0.f},{0.f,0.f,0.f,0.f}};
    const int jq = w * 32 + quad * 8;               // local j within quarter
    const unsigned char* brow = bits + (size_t)(i0 + m) * (NN / 8) + ((q * 1024 + jq) >> 3);
    unsigned int m4[4];
    #pragma unroll
    for (int it = 0; it < 4; ++it) m4[it] = brow[it * 32];

    #pragma unroll
    for (int it = 0; it < 4; ++it) {
        const int jl = jq + it * 256;               // local j
        const int j  = q * 1024 + jl;               // global j
        const unsigned int mb = m4[it];
        const float4 g0 = *(const float4*)(sf2q + jl);
        const float4 g1 = *(const float4*)(sf2q + jl + 4);
        half8 af;
        {
            float u, p;
            u = f1c + g0.x; p = EXP2F(fmaxf(u, fmaf(0.2f, u, c8))); den0 += p; af[0] = (mb & 1u)   ? (_Float16)p : (_Float16)0.f;
            u = f1c + g0.y; p = EXP2F(fmaxf(u, fmaf(0.2f, u, c8))); den1 += p; af[1] = (mb & 2u)   ? (_Float16)p : (_Float16)0.f;
            u = f1c + g0.z; p = EXP2F(fmaxf(u, fmaf(0.2f, u, c8))); den0 += p; af[2] = (mb & 4u)   ? (_Float16)p : (_Float16)0.f;
            u = f1c + g0.w; p = EXP2F(fmaxf(u, fmaf(0.2f, u, c8))); den1 += p; af[3] = (mb & 8u)   ? (_Float16)p : (_Float16)0.f;
            u = f1c + g1.x; p = EXP2F(fmaxf(u, fmaf(0.2f, u, c8))); den0 += p; af[4] = (mb & 16u)  ? (_Float16)p : (_Float16)0.f;
            u = f1c + g1.y; p = EXP2F(fmaxf(u, fmaf(0.2f, u, c8))); den1 += p; af[5] = (mb & 32u)  ? (_Float16)p : (_Float16)0.f;
            u = f1c + g1.z; p = EXP2F(fmaxf(u, fmaf(0.2f, u, c8))); den0 += p; af[6] = (mb & 64u)  ? (_Float16)p : (_Float16)0.f;
            u = f1c + g1.w; p = EXP2F(fmaxf(u, fmaf(0.2f, u, c8))); den1 += p; af[7] = (mb & 128u) ? (_Float16)p : (_Float16)0.f;
        }
        #pragma unroll
        for (int nt = 0; nt < 4; ++nt) {
            const half8 bf = *(const half8*)(WhT + (size_t)(nt * 16 + m) * NN + j);
            acc[nt] = __builtin_amdgcn_mfma_f32_16x16x32_f16(af, bf, acc[nt], 0, 0, 0);
        }
    }
    float den = den0 + den1;
    den += __shfl_xor(den, 16);
    den += __shfl_xor(den, 32);
    if (l < 16) sden[w * 16 + l] = den;
    // D layout (verified): out row = quad*4 + reg, channel = nt*16 + (lane&15)
    #pragma unroll
    for (int nt = 0; nt < 4; ++nt)
        #pragma unroll
        for (int r = 0; r < 4; ++r)
            sacc[w * 1024 + (quad * 4 + r) * 64 + nt * 16 + m] = acc[nt][r];
    __syncthreads();
    // block-partial reduce (8 waves) -> ws partials
    {
        float s0 = 0.f, s1 = 0.f;
        #pragma unroll
        for (int w2 = 0; w2 < 8; ++w2) {
            s0 += sacc[w2 * 1024 + t];
            s1 += sacc[w2 * 1024 + t + 512];
        }
        pout[(size_t)tile * 4096 + q * 1024 + t]       = s0;
        pout[(size_t)tile * 4096 + q * 1024 + t + 512] = s1;
        if (t < 16) {
            float d = 0.f;
            #pragma unroll
            for (int w2 = 0; w2 < 8; ++w2) d += sden[w2 * 16 + t];
            pden[tile * 64 + q * 16 + t] = d;
        }
    }
    // publish partials, then last block of the tile finalizes
    __threadfence();               // device-scope release of this thread's stores
    __syncthreads();               // all threads' fences done
    if (t == 0) slast = atomicAdd(&cnt[tile], 1u);   // device-scope RMW
    __syncthreads();
    if (slast == 3u) {
        __threadfence();           // acquire before reading other blocks' partials
        #pragma unroll
        for (int half = 0; half < 2; ++half) {
            const int o = t + half * 512;
            const int row = o >> 6;
            float v = 0.f, d = 0.f;
            #pragma unroll
            for (int q2 = 0; q2 < 4; ++q2) {
                v += pout[(size_t)tile * 4096 + q2 * 1024 + o];
                d += pden[tile * 64 + q2 * 16 + row];
            }
            out[(size_t)tile * 1024 + o] = elu1(v / d);
        }
    }
}

extern "C" void kernel_launch(void* const* d_in, const int* in_sizes, int n_in,
                              void* d_out, int out_size, void* d_ws, size_t ws_size,
                              hipStream_t stream) {
    const float* H  = (const float*)d_in[0];
    const int* adj  = (const int*)d_in[1];
    const float* W  = (const float*)d_in[2];
    const float* a  = (const float*)d_in[3];
    float* out = (float*)d_out;
    char* ws = (char*)d_ws;
    // ws: WhT 512K | f1 @512K | f2 @528K | blkmax @544K | cnt @545K |
    //     pden @552K (64K) | bits @1M (2M) | pout @4M (4M)
    unsigned short* WhT = (unsigned short*)(ws);
    float* f1          = (float*)(ws + (512 << 10));
    float* f2          = (float*)(ws + (528 << 10));
    float* blkmax      = (float*)(ws + (544 << 10));
    unsigned int* cnt  = (unsigned int*)(ws + (545 << 10));
    float* pden        = (float*)(ws + (552 << 10));
    unsigned int* bits = (unsigned int*)(ws + (1 << 20));
    float* pout        = (float*)(ws + (4 << 20));
    hipLaunchKernelGGL(k_prep, dim3(2304), dim3(256), 0, stream,
                       adj, bits, H, W, a, WhT, f1, f2, blkmax, cnt);
    hipLaunchKernelGGL(k_att,  dim3(1024), dim3(512), 0, stream,
                       (const unsigned char*)bits, (const _Float16*)WhT, f1, f2,
                       blkmax, pout, pden, cnt, out);
}

// Round 5
// 121.748 us; speedup vs baseline: 3.1239x; 3.1239x over previous
//
#include <hip/hip_runtime.h>
#include <math.h>

static constexpr int NN   = 4096;
static constexpr int INC  = 256;
static constexpr int OUTC = 64;

typedef _Float16 half8 __attribute__((ext_vector_type(8)));
typedef float floatx4 __attribute__((ext_vector_type(4)));

#if __has_builtin(__builtin_amdgcn_exp2f)
#define EXP2F(x) __builtin_amdgcn_exp2f(x)
#else
#define EXP2F(x) exp2f(x)
#endif

__device__ __forceinline__ float lrelu(float x) {
    return fmaxf(x, 0.2f * x);
}
__device__ __forceinline__ float elu1(float x) {
    return x > 0.f ? x : (__expf(x) - 1.f);
}

// K_prep: fused independent front-end work, one launch (R1 structure —
// the best-measured configuration; R2/R3 fused-adj and R4 split-tile
// experiments all regressed and are reverted).
//  - blocks 0..255   : Wh = H@W -> fp16 WhT (transposed), f1 = Wh@a1, f2 = Wh@a2
//  - blocks 256..2303: pack adj (64 MB) -> 2 MB bitmask, coalesced via LDS.
__global__ __launch_bounds__(256) void k_prep(const int* __restrict__ adj,
                                              unsigned int* __restrict__ bits,
                                              const float* __restrict__ H,
                                              const float* __restrict__ W,
                                              const float* __restrict__ a,
                                              unsigned short* __restrict__ WhT,
                                              float* __restrict__ f1,
                                              float* __restrict__ f2) {
    __shared__ __align__(16) float Hl[16 * INC];   // 16 KB (pack branch aliases 2 KB)
    __shared__ _Float16 Tl[16 * 68];               // 2.2 KB transpose buffer
    const int t = threadIdx.x;
    if (blockIdx.x >= 256) {
        // ---- pack branch: 2 adj rows (8192 ints = 2048 int4) per block ----
        unsigned char* nib = (unsigned char*)Hl;           // 2 KB LDS alias
        const int blk = blockIdx.x - 256;
        const int4* src = (const int4*)adj + (size_t)blk * 2048;
        #pragma unroll
        for (int k = 0; k < 8; ++k) {
            const int4 v = src[k * 256 + t];               // fully coalesced
            nib[k * 256 + t] = (unsigned char)((unsigned int)(v.x > 0)
                             | ((unsigned int)(v.y > 0) << 1)
                             | ((unsigned int)(v.z > 0) << 2)
                             | ((unsigned int)(v.w > 0) << 3));
        }
        __syncthreads();
        // thread t gathers nibbles of int4 indices 8t..8t+7 -> ints 32t..32t+31
        const unsigned int* n32 = (const unsigned int*)nib;
        unsigned int lo = n32[t * 2 + 0];
        unsigned int hi = n32[t * 2 + 1];
        lo |= lo >> 4;  lo &= 0x00FF00FFu;  lo |= lo >> 8;  lo &= 0x0000FFFFu;
        hi |= hi >> 4;  hi &= 0x00FF00FFu;  hi |= hi >> 8;  hi &= 0x0000FFFFu;
        bits[blk * 256 + t] = lo | (hi << 16);
        return;
    }
    // ---- wh branch ----
    const int i0 = blockIdx.x * 16;
    {
        const float4* H4 = (const float4*)(H + i0 * INC);
        float4* Hl4 = (float4*)Hl;
        #pragma unroll
        for (int u = 0; u < 4; ++u) Hl4[u * 256 + t] = H4[u * 256 + t];
    }
    __syncthreads();
    const int c = t & 63;       // channel (lane)
    const int g = t >> 6;       // wave -> row group
    const float a1c = a[c];
    const float a2c = a[OUTC + c];
    float acc[4] = {0.f, 0.f, 0.f, 0.f};
    const float4* Hl4 = (const float4*)Hl;
    #pragma unroll 4
    for (int k4 = 0; k4 < INC / 4; ++k4) {
        const float w0 = W[(k4 * 4 + 0) * OUTC + c];   // coalesced, L2-hit
        const float w1 = W[(k4 * 4 + 1) * OUTC + c];
        const float w2 = W[(k4 * 4 + 2) * OUTC + c];
        const float w3 = W[(k4 * 4 + 3) * OUTC + c];
        #pragma unroll
        for (int s = 0; s < 4; ++s) {
            const float4 h = Hl4[(g + 4 * s) * (INC / 4) + k4];
            acc[s] = fmaf(h.x, w0, fmaf(h.y, w1, fmaf(h.z, w2, fmaf(h.w, w3, acc[s]))));
        }
    }
    #pragma unroll
    for (int s = 0; s < 4; ++s) {
        const int r = g + 4 * s;
        Tl[r * 68 + c] = (_Float16)acc[s];
        float v1 = acc[s] * a1c;
        float v2 = acc[s] * a2c;
        #pragma unroll
        for (int off = 32; off; off >>= 1) {
            v1 += __shfl_xor(v1, off);
            v2 += __shfl_xor(v2, off);
        }
        if (c == 0) { f1[i0 + r] = v1; f2[i0 + r] = v2; }
    }
    __syncthreads();
    const int c2 = t >> 2;
    const int rs = (t & 3) * 4;
    ushort4 u;
    u.x = *(const unsigned short*)&Tl[(rs + 0) * 68 + c2];
    u.y = *(const unsigned short*)&Tl[(rs + 1) * 68 + c2];
    u.z = *(const unsigned short*)&Tl[(rs + 2) * 68 + c2];
    u.w = *(const unsigned short*)&Tl[(rs + 3) * 68 + c2];
    *(ushort4*)(WhT + c2 * NN + i0 + rs) = u;
}

// K_att: fused attention, 16 rows x all 4096 j per block, 16 waves (R1).
// adj mask from the 2 MB bitmask (L2-resident, 1 byte per lane-iter).
// Inner loop: sf2 pre-scaled by log2e in LDS, so each element is
// add + fmaf + fmax + exp2 (4 ops; was 5) — math identical to R1
// (verified correct in R4's bench with the same absmax).
__global__ __launch_bounds__(1024, 4) void k_att(const unsigned char* __restrict__ bits,
                                                 const _Float16* __restrict__ WhT,
                                                 const float* __restrict__ f1,
                                                 const float* __restrict__ f2,
                                                 float* __restrict__ out) {
    __shared__ __align__(16) float sf2[NN];         // 16 KB (f2 * log2e)
    __shared__ __align__(16) float sacc[16 * 1024]; // 64 KB
    __shared__ float sden[16 * 16];
    __shared__ float smax[16];
    const int t = threadIdx.x;
    const int w = t >> 6;          // wave 0..15
    const int l = t & 63;
    const int m = l & 15;          // A row (= output row within tile)
    const int quad = l >> 4;       // k-group
    const int i0 = blockIdx.x * 16;
    const float LOG2E = 1.44269504f;

    // pre-pass: f2 -> LDS (pre-scaled), block max (on raw values)
    {
        float4 v = ((const float4*)f2)[t];
        float mloc = fmaxf(fmaxf(v.x, v.y), fmaxf(v.z, v.w));
        v.x *= LOG2E; v.y *= LOG2E; v.z *= LOG2E; v.w *= LOG2E;
        ((float4*)sf2)[t] = v;
        #pragma unroll
        for (int off = 32; off; off >>= 1) mloc = fmaxf(mloc, __shfl_xor(mloc, off));
        if (l == 0) smax[w] = mloc;
    }
    __syncthreads();
    float maxf2 = smax[0];
    #pragma unroll
    for (int k = 1; k < 16; ++k) maxf2 = fmaxf(maxf2, smax[k]);

    const float f1r = f1[i0 + m];
    const float mrow = lrelu(f1r + maxf2);  // exact per-row softmax max (lrelu monotone)
    const float nm2 = -mrow * LOG2E;        // exp(lrelu(z)-mrow) = exp2(max(u, 0.2u+c8))
    const float f1c = fmaf(f1r, LOG2E, nm2);//   with u = f1c + f2j*log2e
    const float c8 = 0.8f * nm2;
    float den0 = 0.f, den1 = 0.f;
    floatx4 acc[4] = {{0.f,0.f,0.f,0.f},{0.f,0.f,0.f,0.f},{0.f,0.f,0.f,0.f},{0.f,0.f,0.f,0.f}};
    const int jbase = w * 32 + quad * 8;
    const unsigned char* brow = bits + (size_t)(i0 + m) * (NN / 8) + (jbase >> 3);
    unsigned int m8[8];
    #pragma unroll
    for (int it = 0; it < 8; ++it) m8[it] = brow[it * 64];

    #pragma unroll 2
    for (int it = 0; it < 8; ++it) {
        const int j = jbase + it * 512;
        const unsigned int mb = m8[it];
        const float4 g0 = *(const float4*)(sf2 + j);
        const float4 g1 = *(const float4*)(sf2 + j + 4);
        half8 af;
        {
            float u, p;
            u = f1c + g0.x; p = EXP2F(fmaxf(u, fmaf(0.2f, u, c8))); den0 += p; af[0] = (mb & 1u)   ? (_Float16)p : (_Float16)0.f;
            u = f1c + g0.y; p = EXP2F(fmaxf(u, fmaf(0.2f, u, c8))); den1 += p; af[1] = (mb & 2u)   ? (_Float16)p : (_Float16)0.f;
            u = f1c + g0.z; p = EXP2F(fmaxf(u, fmaf(0.2f, u, c8))); den0 += p; af[2] = (mb & 4u)   ? (_Float16)p : (_Float16)0.f;
            u = f1c + g0.w; p = EXP2F(fmaxf(u, fmaf(0.2f, u, c8))); den1 += p; af[3] = (mb & 8u)   ? (_Float16)p : (_Float16)0.f;
            u = f1c + g1.x; p = EXP2F(fmaxf(u, fmaf(0.2f, u, c8))); den0 += p; af[4] = (mb & 16u)  ? (_Float16)p : (_Float16)0.f;
            u = f1c + g1.y; p = EXP2F(fmaxf(u, fmaf(0.2f, u, c8))); den1 += p; af[5] = (mb & 32u)  ? (_Float16)p : (_Float16)0.f;
            u = f1c + g1.z; p = EXP2F(fmaxf(u, fmaf(0.2f, u, c8))); den0 += p; af[6] = (mb & 64u)  ? (_Float16)p : (_Float16)0.f;
            u = f1c + g1.w; p = EXP2F(fmaxf(u, fmaf(0.2f, u, c8))); den1 += p; af[7] = (mb & 128u) ? (_Float16)p : (_Float16)0.f;
        }
        #pragma unroll
        for (int nt = 0; nt < 4; ++nt) {
            const half8 bf = *(const half8*)(WhT + (size_t)(nt * 16 + m) * NN + j);
            acc[nt] = __builtin_amdgcn_mfma_f32_16x16x32_f16(af, bf, acc[nt], 0, 0, 0);
        }
    }
    float den = den0 + den1;
    den += __shfl_xor(den, 16);
    den += __shfl_xor(den, 32);
    if (l < 16) sden[w * 16 + l] = den;
    // D layout (verified): out row = quad*4 + reg, channel = nt*16 + (lane&15)
    #pragma unroll
    for (int nt = 0; nt < 4; ++nt)
        #pragma unroll
        for (int r = 0; r < 4; ++r)
            sacc[w * 1024 + (quad * 4 + r) * 64 + nt * 16 + m] = acc[nt][r];
    __syncthreads();
    float s = 0.f;
    #pragma unroll
    for (int w2 = 0; w2 < 16; ++w2) s += sacc[w2 * 1024 + t];
    float dden = 0.f;
    const int row = t >> 6;
    #pragma unroll
    for (int w2 = 0; w2 < 16; ++w2) dden += sden[w2 * 16 + row];
    out[(size_t)i0 * OUTC + t] = elu1(s / dden);
}

extern "C" void kernel_launch(void* const* d_in, const int* in_sizes, int n_in,
                              void* d_out, int out_size, void* d_ws, size_t ws_size,
                              hipStream_t stream) {
    const float* H  = (const float*)d_in[0];
    const int* adj  = (const int*)d_in[1];
    const float* W  = (const float*)d_in[2];
    const float* a  = (const float*)d_in[3];
    float* out = (float*)d_out;
    char* ws = (char*)d_ws;
    // ws: WhT 512K | f1 16K | f2 16K | bits 2M @ 1M
    unsigned short* WhT = (unsigned short*)(ws);
    float* f1 = (float*)(ws + (512 << 10));
    float* f2 = (float*)(ws + (528 << 10));
    unsigned int* bits = (unsigned int*)(ws + (1 << 20));
    hipLaunchKernelGGL(k_prep, dim3(2304), dim3(256), 0, stream,
                       adj, bits, H, W, a, WhT, f1, f2);
    hipLaunchKernelGGL(k_att,  dim3(256),  dim3(1024), 0, stream,
                       (const unsigned char*)bits, (const _Float16*)WhT, f1, f2, out);
}